// Round 11
// baseline (3699.634 us; speedup 1.0000x reference)
//
#include <hip/hip_runtime.h>

#define NN 50000
#define NE 800000
#define D  128
#define RT 32
#define ND ((size_t)NN * D)

typedef unsigned short u16;
typedef unsigned int   u32;
typedef long long      ll64;

__device__ __forceinline__ float bf2f(u16 v) {
  return __uint_as_float(((u32)v) << 16);
}
__device__ __forceinline__ float bflo(u32 u) { return __uint_as_float(u << 16); }
__device__ __forceinline__ float bfhi(u32 u) { return __uint_as_float(u & 0xffff0000u); }
__device__ __forceinline__ float ldf(const void* p, size_t i, int isf32) {
  return isf32 ? ((const float*)p)[i] : bf2f(((const u16*)p)[i]);
}
__device__ __forceinline__ int lde(const void* p, size_t i, int isi64) {
  return isi64 ? (int)((const ll64*)p)[i] : ((const int*)p)[i];
}

// flags: [0]=floats-are-f32, [1]=edges-are-i64
__global__ void k_detect(const void* __restrict__ feat, const void* __restrict__ edges,
                         int* __restrict__ flags) {
  __shared__ int cnt0, cnt1;
  int t = threadIdx.x;
  if (t == 0) { cnt0 = 0; cnt1 = 0; }
  __syncthreads();
  float v = ((const float*)feat)[t];
  float av = fabsf(v);
  if (av == 0.f || (av >= 1e-8f && av <= 1e4f)) atomicAdd(&cnt0, 1);
  if (t < 128) {
    if (((const int*)edges)[2 * t + 1] != 0) atomicAdd(&cnt1, 1);
  }
  __syncthreads();
  if (t == 0) {
    flags[0] = (cnt0 >= 240) ? 1 : 0;
    flags[1] = (cnt1 == 0) ? 1 : 0;
  }
}

// ---- per-relation init: emb(f32 ws) = features; rel_cur = rel_emb[k] ----
__global__ void k_initk(const void* __restrict__ feat, const void* __restrict__ rel_emb,
                        float* __restrict__ emb, float* __restrict__ rel_cur, int k,
                        const int* __restrict__ flags) {
  int isf32 = flags[0];
  size_t i = (size_t)blockIdx.x * 256 + threadIdx.x;
  if (isf32) {
    ((float4*)emb)[i] = ((const float4*)feat)[i];
  } else {
    uint2 v = ((const uint2*)feat)[i];
    ((float4*)emb)[i] = make_float4(bflo(v.x), bfhi(v.x), bflo(v.y), bfhi(v.y));
  }
  if (blockIdx.x == 0 && threadIdx.x < D)
    rel_cur[threadIdx.x] = ldf(rel_emb, (size_t)k * D + threadIdx.x, isf32);
}

// ---------------- CSR build (listing semantics; verified r9) ----------------
__global__ void k_count(const void* __restrict__ edges, int* __restrict__ deg, const int* __restrict__ flags) {
  int isi64 = flags[1];
  int k = blockIdx.y;
  int e = blockIdx.x * 256 + threadIdx.x;
  int dst = lde(edges, (size_t)k * 2 * NE + NE + e, isi64);
  atomicAdd(&deg[k * NN + dst], 1);
}

__global__ void k_scan(const int* __restrict__ deg, int* __restrict__ rowp, int* __restrict__ cur) {
  int k = blockIdx.x;
  __shared__ int s[256];
  int t = threadIdx.x;
  int running = 0;
  if (t == 0) rowp[(size_t)k * (NN + 1)] = 0;
  for (int base = 0; base < NN; base += 256) {
    int idx = base + t;
    int v = (idx < NN) ? deg[k * NN + idx] : 0;
    s[t] = v; __syncthreads();
    #pragma unroll
    for (int off = 1; off < 256; off <<= 1) {
      int a = (t >= off) ? s[t - off] : 0;
      __syncthreads();
      s[t] += a;
      __syncthreads();
    }
    int incl = s[t];
    if (idx < NN) {
      rowp[(size_t)k * (NN + 1) + idx + 1] = running + incl;
      cur[k * NN + idx] = running + incl - v;
    }
    int tot = s[255];
    __syncthreads();
    running += tot;
  }
}

__global__ void k_scatter(const void* __restrict__ edges, int* __restrict__ cur,
                          u16* __restrict__ colx, const int* __restrict__ flags) {
  int isi64 = flags[1];
  int k = blockIdx.y;
  int e = blockIdx.x * 256 + threadIdx.x;
  int src = lde(edges, (size_t)k * 2 * NE + e, isi64);
  int dst = lde(edges, (size_t)k * 2 * NE + NE + e, isi64);
  int pos = atomicAdd(&cur[k * NN + dst], 1);
  colx[(size_t)k * NE + pos] = (u16)src;
}

// ---- prep: Bm = diag(rel)@W; wsv/wdv = Bm@a; zero stats ----
__global__ void k_prep(const void* __restrict__ gatW, const void* __restrict__ asrc,
                       const void* __restrict__ adst, const float* __restrict__ rel_cur,
                       int layer, float* __restrict__ Bm,
                       float* __restrict__ wsv, float* __restrict__ wdv,
                       float* __restrict__ colsum, float* __restrict__ colvar,
                       const int* __restrict__ flags) {
  int isf32 = flags[0];
  int r = threadIdx.x;
  float rv = rel_cur[r];
  size_t Wo = (size_t)layer * D * D + (size_t)r * D;
  float s = 0.f, d = 0.f;
  for (int c = 0; c < D; c++) {
    float b = rv * ldf(gatW, Wo + c, isf32);
    Bm[r * D + c] = b;
    s += b * ldf(asrc, layer * D + c, isf32);
    d += b * ldf(adst, layer * D + c, isf32);
  }
  wsv[r] = s; wdv[r] = d;
  colsum[r] = 0.f; colvar[r] = 0.f;
}

// ---------------- GEMM: h(f32) = x @ Bm ----------------
__launch_bounds__(256)
__global__ void k_gemm(const float* __restrict__ x, const float* __restrict__ Bm,
                       float* __restrict__ h) {
  __shared__ float xl[RT * D];
  int t = threadIdx.x;
  int row0 = blockIdx.x * RT;

  for (int i = t; i < RT * D / 4; i += 256) {
    int r = i >> 5;
    int row = row0 + r;
    float4 v = make_float4(0.f, 0.f, 0.f, 0.f);
    if (row < NN) v = ((const float4*)(x + (size_t)row * D))[i & 31];
    ((float4*)xl)[i] = v;
  }
  __syncthreads();

  int cg = t & 31, rg = t >> 5;
  float acc0[4], acc1[4], acc2[4], acc3[4];
  #pragma unroll
  for (int j = 0; j < 4; j++) { acc0[j] = 0; acc1[j] = 0; acc2[j] = 0; acc3[j] = 0; }
  const float* Bp = Bm + cg * 4;
  const float* xp = xl + (rg * 4) * D;
  for (int kk = 0; kk < D; kk += 4) {
    float4 b0 = *(const float4*)(Bp + (kk    ) * D);
    float4 b1 = *(const float4*)(Bp + (kk + 1) * D);
    float4 b2 = *(const float4*)(Bp + (kk + 2) * D);
    float4 b3 = *(const float4*)(Bp + (kk + 3) * D);
    #pragma unroll
    for (int j = 0; j < 4; j++) {
      float4 x4 = *(const float4*)(xp + j * D + kk);
      acc0[j] += x4.x * b0.x + x4.y * b1.x + x4.z * b2.x + x4.w * b3.x;
      acc1[j] += x4.x * b0.y + x4.y * b1.y + x4.z * b2.y + x4.w * b3.y;
      acc2[j] += x4.x * b0.z + x4.y * b1.z + x4.z * b2.z + x4.w * b3.z;
      acc3[j] += x4.x * b0.w + x4.y * b1.w + x4.z * b2.w + x4.w * b3.w;
    }
  }
  #pragma unroll
  for (int j = 0; j < 4; j++) {
    int row = row0 + rg * 4 + j;
    if (row < NN)
      ((float4*)(h + (size_t)row * D))[cg] = make_float4(acc0[j], acc1[j], acc2[j], acc3[j]);
  }
}

// ---------------- alphas ----------------
__global__ void k_alpha(const float* __restrict__ x, const float* __restrict__ wsv,
                        const float* __restrict__ wdv, float* __restrict__ av_s, float* __restrict__ av_d) {
  __shared__ float ws[D], wd[D];
  int t = threadIdx.x;
  if (t < D) { ws[t] = wsv[t]; wd[t] = wdv[t]; }
  __syncthreads();
  int n = blockIdx.x * 256 + t;
  if (n >= NN) return;
  const float4* row = (const float4*)(x + (size_t)n * D);
  float s = 0.f, d = 0.f;
  for (int g = 0; g < 32; g++) {
    float4 v = row[g];
    int c = g * 4;
    s += v.x * ws[c] + v.y * ws[c + 1] + v.z * ws[c + 2] + v.w * ws[c + 3];
    d += v.x * wd[c] + v.y * wd[c + 1] + v.z * wd[c + 2] + v.w * wd[c + 3];
  }
  av_s[n] = s; av_d[n] = d;
}

// ---------------- agg phase 1: per-node max + 1/denom ----------------
__global__ void k_mden(const int* __restrict__ rowp, const u16* __restrict__ colx,
                       const float* __restrict__ av_s, const float* __restrict__ av_d,
                       int k, float* __restrict__ mn, float* __restrict__ dinv) {
  int n = blockIdx.x * 256 + threadIdx.x;
  if (n >= NN) return;
  const int* rp = rowp + (size_t)k * (NN + 1);
  int s0 = rp[n], s1 = rp[n + 1];
  float ad = av_d[n];
  const u16* cl = colx + (size_t)k * NE;
  float m = -INFINITY;
  for (int q = s0; q < s1; q++) {
    float e = av_s[cl[q]] + ad;
    e = e > 0.f ? e : 0.2f * e;
    m = fmaxf(m, e);
  }
  float den = 0.f;
  for (int q = s0; q < s1; q++) {
    float e = av_s[cl[q]] + ad;
    e = e > 0.f ? e : 0.2f * e;
    den += __expf(e - m);
  }
  mn[n] = m;
  dinv[n] = 1.f / (den + 1e-16f);
}

// ---------------- agg phase 2: wave per node; OUTPUT IS FLOAT32 ----------------
__launch_bounds__(256)
__global__ void k_aggc(const int* __restrict__ rowp, const u16* __restrict__ colx,
                       const float* __restrict__ av_s, const float* __restrict__ av_d,
                       const float* __restrict__ h, const void* __restrict__ gatb,
                       const float* __restrict__ mn, const float* __restrict__ dinv,
                       int layer, int k, float* __restrict__ outf,
                       const int* __restrict__ flags) {
  int isf32 = flags[0];
  int n = blockIdx.x * 4 + (threadIdx.x >> 6);
  int lane = threadIdx.x & 63;
  const int* rp = rowp + (size_t)k * (NN + 1);
  int s0 = rp[n], s1 = rp[n + 1];
  float ad = av_d[n], m = mn[n], di = dinv[n];
  const u16* cl = colx + (size_t)k * NE;
  float a0 = 0.f, a1 = 0.f;
  for (int q = s0; q < s1; q++) {
    int s = cl[q];
    float e = av_s[s] + ad;
    e = e > 0.f ? e : 0.2f * e;
    float p = __expf(e - m);
    float2 hv = *(const float2*)(h + (size_t)s * D + 2 * lane);
    a0 += p * hv.x;
    a1 += p * hv.y;
  }
  float o0 = a0 * di + ldf(gatb, (size_t)layer * D + 2 * lane, isf32);
  float o1 = a1 * di + ldf(gatb, (size_t)layer * D + 2 * lane + 1, isf32);
  *(float2*)(outf + (size_t)n * D + 2 * lane) = make_float2(o0, o1);
}

// ---------------- BN (two-pass) ----------------
__global__ void k_colsum(const float* __restrict__ tmp, float* __restrict__ colsum) {
  __shared__ float s1[256];
  int t = threadIdx.x;
  int c = t & 127;
  int half = t >> 7;
  size_t base = (size_t)blockIdx.x * 256;
  float s = 0.f;
  for (int i = half; i < 256; i += 2) {
    size_t r = base + i;
    if (r < NN) s += tmp[r * D + c];
  }
  s1[t] = s; __syncthreads();
  if (t < 128) atomicAdd(&colsum[c], s1[t] + s1[t + 128]);
}

__global__ void k_mu(const float* __restrict__ colsum, float* __restrict__ mu) {
  int c = threadIdx.x;
  mu[c] = colsum[c] * (1.f / NN);
}

__global__ void k_colvar(const float* __restrict__ tmp, const float* __restrict__ mu,
                         float* __restrict__ colvar) {
  __shared__ float s1[256];
  __shared__ float ml[D];
  int t = threadIdx.x;
  if (t < D) ml[t] = mu[t];
  __syncthreads();
  int c = t & 127;
  int half = t >> 7;
  float mc = ml[c];
  size_t base = (size_t)blockIdx.x * 256;
  float s = 0.f;
  for (int i = half; i < 256; i += 2) {
    size_t r = base + i;
    if (r < NN) {
      float d = tmp[r * D + c] - mc;
      s += d * d;
    }
  }
  s1[t] = s; __syncthreads();
  if (t < 128) atomicAdd(&colvar[c], s1[t] + s1[t + 128]);
}

__global__ void k_bnfin(const float* __restrict__ colvar, float* __restrict__ rsig) {
  int c = threadIdx.x;
  rsig[c] = rsqrtf(colvar[c] * (1.f / NN) + 1e-5f);
}

// ---------------- residual update ----------------
__global__ void k_update(float* __restrict__ e, const float* __restrict__ tmp,
                         const float* __restrict__ mu, const float* __restrict__ rsig,
                         const void* __restrict__ gamma, const void* __restrict__ beta,
                         int layer, const int* __restrict__ flags) {
  int isf32 = flags[0];
  size_t idx = (size_t)blockIdx.x * 256 + threadIdx.x;
  int c0 = ((int)(idx & 31)) * 4;
  float4 t4 = ((const float4*)tmp)[idx];
  float4 e4 = ((float4*)e)[idx];
  float tb[4] = {t4.x, t4.y, t4.z, t4.w};
  float eb[4] = {e4.x, e4.y, e4.z, e4.w};
  #pragma unroll
  for (int i = 0; i < 4; i++) {
    int c = c0 + i;
    float bn = ldf(gamma, (size_t)layer * D + c, isf32) * (tb[i] - mu[c]) * rsig[c]
             + ldf(beta, (size_t)layer * D + c, isf32);
    bn = bn > 0.f ? bn : 0.01f * bn;
    eb[i] += bn;
  }
  ((float4*)e)[idx] = make_float4(eb[0], eb[1], eb[2], eb[3]);
}

// ---------------- rel update; final-layer writes FLOAT32 rel to out ----------------
__global__ void k_relup(const void* __restrict__ relW, const void* __restrict__ relb,
                        float* __restrict__ rel_cur, int layer, float* __restrict__ out_final,
                        const int* __restrict__ flags) {
  int isf32 = flags[0];
  __shared__ float rl[D];
  int c = threadIdx.x;
  rl[c] = rel_cur[c];
  __syncthreads();
  float acc = ldf(relb, (size_t)layer * D + c, isf32);
  size_t Wo = ((size_t)layer * D + c) * D;
  for (int kk = 0; kk < D; kk++) acc += ldf(relW, Wo + kk, isf32) * rl[kk];
  rel_cur[c] = acc;
  if (out_final) out_final[c] = acc;
}

extern "C" void kernel_launch(void* const* d_in, const int* in_sizes, int n_in,
                              void* d_out, int out_size, void* d_ws, size_t ws_size,
                              hipStream_t stream) {
  const void* feat    = d_in[0];
  const void* rel_emb = d_in[1];
  const void* edges   = d_in[2];
  const void* gatW    = d_in[3];
  const void* asrc    = d_in[4];
  const void* adst    = d_in[5];
  const void* gatb    = d_in[6];
  const void* gamma   = d_in[7];
  const void* beta    = d_in[8];
  const void* relW    = d_in[9];
  const void* relb    = d_in[10];
  float* out = (float*)d_out;     // FLOAT32: [4][NN][D] embs + [4][D] rels

  char* p = (char*)d_ws;
  auto take = [&](size_t bytes) -> void* {
    void* r = (void*)p;
    p += (bytes + 255) & ~(size_t)255;
    return r;
  };
  float* emb    = (float*)take(ND * 4);
  float* h      = (float*)take(ND * 4);
  float* tmp    = (float*)take(ND * 4);
  u16*   colx   = (u16*)  take((size_t)4 * NE * 2);
  int*   rowp   = (int*)  take((size_t)4 * (NN + 1) * 4);
  int*   cur    = (int*)  take((size_t)4 * NN * 4);
  int*   deg    = (int*)  take((size_t)4 * NN * 4);
  float* av_s   = (float*)take(NN * 4);
  float* av_d   = (float*)take(NN * 4);
  float* mn     = (float*)take(NN * 4);
  float* dinv   = (float*)take(NN * 4);
  float* Bm     = (float*)take(D * D * 4);
  float* wsv    = (float*)take(D * 4);
  float* wdv    = (float*)take(D * 4);
  float* relc   = (float*)take(D * 4);
  float* colsum = (float*)take(D * 4);
  float* colvar = (float*)take(D * 4);
  float* mu     = (float*)take(D * 4);
  float* rsig   = (float*)take(D * 4);
  int*   flags  = (int*)  take(64);

  hipMemsetAsync(deg, 0, (size_t)4 * NN * 4, stream);

  k_detect<<<1, 256, 0, stream>>>(feat, edges, flags);
  k_count<<<dim3(NE / 256, 4), 256, 0, stream>>>(edges, deg, flags);
  k_scan<<<4, 256, 0, stream>>>(deg, rowp, cur);
  k_scatter<<<dim3(NE / 256, 4), 256, 0, stream>>>(edges, cur, colx, flags);

  for (int k = 0; k < 4; k++) {
    k_initk<<<(int)(ND / 4 / 256), 256, 0, stream>>>(feat, rel_emb, emb, relc, k, flags);
    for (int layer = 0; layer < 3; layer++) {
      bool last = (layer == 2);
      k_prep<<<1, 128, 0, stream>>>(gatW, asrc, adst, relc, layer, Bm, wsv, wdv, colsum, colvar, flags);
      k_gemm<<<(NN + RT - 1) / RT, 256, 0, stream>>>(emb, Bm, h);
      k_alpha<<<(NN + 255) / 256, 256, 0, stream>>>(emb, wsv, wdv, av_s, av_d);
      k_mden<<<(NN + 255) / 256, 256, 0, stream>>>(rowp, colx, av_s, av_d, k, mn, dinv);
      if (!last) {
        k_aggc<<<NN / 4, 256, 0, stream>>>(rowp, colx, av_s, av_d, h, gatb, mn, dinv,
                                           layer, k, tmp, flags);
        k_colsum<<<(NN + 255) / 256, 256, 0, stream>>>(tmp, colsum);
        k_mu<<<1, 128, 0, stream>>>(colsum, mu);
        k_colvar<<<(NN + 255) / 256, 256, 0, stream>>>(tmp, mu, colvar);
        k_bnfin<<<1, 128, 0, stream>>>(colvar, rsig);
        k_update<<<(int)(ND / 4 / 256), 256, 0, stream>>>(emb, tmp, mu, rsig, gamma, beta, layer, flags);
        k_relup<<<1, 128, 0, stream>>>(relW, relb, relc, layer, (float*)nullptr, flags);
      } else {
        k_aggc<<<NN / 4, 256, 0, stream>>>(rowp, colx, av_s, av_d, h, gatb, mn, dinv,
                                           layer, k, out + (size_t)k * ND, flags);
        k_relup<<<1, 128, 0, stream>>>(relW, relb, relc, layer, out + 4 * ND + (size_t)k * D, flags);
      }
    }
  }
}

// Round 12
// 3415.239 us; speedup vs baseline: 1.0833x; 1.0833x over previous
//
#include <hip/hip_runtime.h>

#define NN 50000
#define NE 800000
#define D  128
#define RT 32
#define ND ((size_t)NN * D)

typedef unsigned short u16;
typedef unsigned int   u32;
typedef long long      ll64;

__device__ __forceinline__ float bf2f(u16 v) {
  return __uint_as_float(((u32)v) << 16);
}
__device__ __forceinline__ u16 f2bf(float f) {
  u32 u = __float_as_uint(f);
  u32 r = u + 0x7fffu + ((u >> 16) & 1u);   // RNE
  return (u16)(r >> 16);
}
__device__ __forceinline__ float bflo(u32 u) { return __uint_as_float(u << 16); }
__device__ __forceinline__ float bfhi(u32 u) { return __uint_as_float(u & 0xffff0000u); }
__device__ __forceinline__ float ldf(const void* p, size_t i, int isf32) {
  return isf32 ? ((const float*)p)[i] : bf2f(((const u16*)p)[i]);
}
__device__ __forceinline__ int lde(const void* p, size_t i, int isi64) {
  return isi64 ? (int)((const ll64*)p)[i] : ((const int*)p)[i];
}

// flags: [0]=floats-are-f32, [1]=edges-are-i64
__global__ void k_detect(const void* __restrict__ feat, const void* __restrict__ edges,
                         int* __restrict__ flags) {
  __shared__ int cnt0, cnt1;
  int t = threadIdx.x;
  if (t == 0) { cnt0 = 0; cnt1 = 0; }
  __syncthreads();
  float v = ((const float*)feat)[t];
  float av = fabsf(v);
  if (av == 0.f || (av >= 1e-8f && av <= 1e4f)) atomicAdd(&cnt0, 1);
  if (t < 128) {
    if (((const int*)edges)[2 * t + 1] != 0) atomicAdd(&cnt1, 1);
  }
  __syncthreads();
  if (t == 0) {
    flags[0] = (cnt0 >= 240) ? 1 : 0;
    flags[1] = (cnt1 == 0) ? 1 : 0;
  }
}

// ---- per-relation init: emb(f32 ws) = features; rel_cur = rel_emb[k] ----
__global__ void k_initk(const void* __restrict__ feat, const void* __restrict__ rel_emb,
                        float* __restrict__ emb, float* __restrict__ rel_cur, int k,
                        const int* __restrict__ flags) {
  int isf32 = flags[0];
  size_t i = (size_t)blockIdx.x * 256 + threadIdx.x;
  if (isf32) {
    ((float4*)emb)[i] = ((const float4*)feat)[i];
  } else {
    uint2 v = ((const uint2*)feat)[i];
    ((float4*)emb)[i] = make_float4(bflo(v.x), bfhi(v.x), bflo(v.y), bfhi(v.y));
  }
  if (blockIdx.x == 0 && threadIdx.x < D)
    rel_cur[threadIdx.x] = ldf(rel_emb, (size_t)k * D + threadIdx.x, isf32);
}

// ---------------- CSR build ----------------
__global__ void k_count(const void* __restrict__ edges, int* __restrict__ deg, const int* __restrict__ flags) {
  int isi64 = flags[1];
  int k = blockIdx.y;
  int e = blockIdx.x * 256 + threadIdx.x;
  int dst = lde(edges, (size_t)k * 2 * NE + NE + e, isi64);
  atomicAdd(&deg[k * NN + dst], 1);
}

__global__ void k_scan(const int* __restrict__ deg, int* __restrict__ rowp, int* __restrict__ cur) {
  int k = blockIdx.x;
  __shared__ int s[256];
  int t = threadIdx.x;
  int running = 0;
  if (t == 0) rowp[(size_t)k * (NN + 1)] = 0;
  for (int base = 0; base < NN; base += 256) {
    int idx = base + t;
    int v = (idx < NN) ? deg[k * NN + idx] : 0;
    s[t] = v; __syncthreads();
    #pragma unroll
    for (int off = 1; off < 256; off <<= 1) {
      int a = (t >= off) ? s[t - off] : 0;
      __syncthreads();
      s[t] += a;
      __syncthreads();
    }
    int incl = s[t];
    if (idx < NN) {
      rowp[(size_t)k * (NN + 1) + idx + 1] = running + incl;
      cur[k * NN + idx] = running + incl - v;
    }
    int tot = s[255];
    __syncthreads();
    running += tot;
  }
}

__global__ void k_scatter(const void* __restrict__ edges, int* __restrict__ cur,
                          u32* __restrict__ colx, const int* __restrict__ flags) {
  int isi64 = flags[1];
  int k = blockIdx.y;
  int e = blockIdx.x * 256 + threadIdx.x;
  int src = lde(edges, (size_t)k * 2 * NE + e, isi64);
  int dst = lde(edges, (size_t)k * 2 * NE + NE + e, isi64);
  int pos = atomicAdd(&cur[k * NN + dst], 1);
  colx[(size_t)k * NE + pos] = (u32)src;
}

// ---- prep: Bm = diag(rel)@W; wsv/wdv = Bm@a; zero stats ----
__global__ void k_prep(const void* __restrict__ gatW, const void* __restrict__ asrc,
                       const void* __restrict__ adst, const float* __restrict__ rel_cur,
                       int layer, float* __restrict__ Bm,
                       float* __restrict__ wsv, float* __restrict__ wdv,
                       float* __restrict__ colsum, float* __restrict__ colvar,
                       const int* __restrict__ flags) {
  int isf32 = flags[0];
  int r = threadIdx.x;
  float rv = rel_cur[r];
  size_t Wo = (size_t)layer * D * D + (size_t)r * D;
  float s = 0.f, d = 0.f;
  for (int c = 0; c < D; c++) {
    float b = rv * ldf(gatW, Wo + c, isf32);
    Bm[r * D + c] = b;
    s += b * ldf(asrc, layer * D + c, isf32);
    d += b * ldf(adst, layer * D + c, isf32);
  }
  wsv[r] = s; wdv[r] = d;
  colsum[r] = 0.f; colvar[r] = 0.f;
}

// ------- GEMM: hb(bf16 packed) = x @ Bm; fused alpha epilogue -------
__launch_bounds__(256)
__global__ void k_gemm(const float* __restrict__ x, const float* __restrict__ Bm,
                       const float* __restrict__ wsv, const float* __restrict__ wdv,
                       u32* __restrict__ hb, float* __restrict__ av_s, float* __restrict__ av_d) {
  __shared__ float xl[RT * D];     // 16 KB
  __shared__ float wsl[D], wdl[D];
  int t = threadIdx.x;
  int row0 = blockIdx.x * RT;

  if (t < D) { wsl[t] = wsv[t]; wdl[t] = wdv[t]; }
  for (int i = t; i < RT * D / 4; i += 256) {
    int r = i >> 5;
    int row = row0 + r;
    float4 v = make_float4(0.f, 0.f, 0.f, 0.f);
    if (row < NN) v = ((const float4*)(x + (size_t)row * D))[i & 31];
    ((float4*)xl)[i] = v;
  }
  __syncthreads();

  int cg = t & 31, rg = t >> 5;
  float acc0[4], acc1[4], acc2[4], acc3[4];
  #pragma unroll
  for (int j = 0; j < 4; j++) { acc0[j] = 0; acc1[j] = 0; acc2[j] = 0; acc3[j] = 0; }
  const float* Bp = Bm + cg * 4;
  const float* xp = xl + (rg * 4) * D;
  for (int kk = 0; kk < D; kk += 4) {
    float4 b0 = *(const float4*)(Bp + (kk    ) * D);
    float4 b1 = *(const float4*)(Bp + (kk + 1) * D);
    float4 b2 = *(const float4*)(Bp + (kk + 2) * D);
    float4 b3 = *(const float4*)(Bp + (kk + 3) * D);
    #pragma unroll
    for (int j = 0; j < 4; j++) {
      float4 x4 = *(const float4*)(xp + j * D + kk);
      acc0[j] += x4.x * b0.x + x4.y * b1.x + x4.z * b2.x + x4.w * b3.x;
      acc1[j] += x4.x * b0.y + x4.y * b1.y + x4.z * b2.y + x4.w * b3.y;
      acc2[j] += x4.x * b0.z + x4.y * b1.z + x4.z * b2.z + x4.w * b3.z;
      acc3[j] += x4.x * b0.w + x4.y * b1.w + x4.z * b2.w + x4.w * b3.w;
    }
  }
  #pragma unroll
  for (int j = 0; j < 4; j++) {
    int row = row0 + rg * 4 + j;
    if (row < NN) {
      uint2 pk;
      pk.x = (u32)f2bf(acc0[j]) | ((u32)f2bf(acc1[j]) << 16);
      pk.y = (u32)f2bf(acc2[j]) | ((u32)f2bf(acc3[j]) << 16);
      *(uint2*)(hb + (size_t)row * 64 + cg * 2) = pk;
    }
  }
  // alpha epilogue: threads 0..31, one row each; rotated LDS reads (conflict-free)
  if (t < RT) {
    int row = row0 + t;
    if (row < NN) {
      const float* xr = xl + t * D;
      float s = 0.f, d = 0.f;
      for (int kk = 0; kk < D; kk++) {
        int c = (kk + t) & (D - 1);
        float xv = xr[c];
        s += xv * wsl[c];
        d += xv * wdl[c];
      }
      av_s[row] = s; av_d[row] = d;
    }
  }
}

// ------- fused aggregation: wave per node; in-wave max/denom; bf16 h -------
__launch_bounds__(256)
__global__ void k_aggf(const int* __restrict__ rowp, const u32* __restrict__ colx,
                       const float* __restrict__ av_s, const float* __restrict__ av_d,
                       const u32* __restrict__ hb, const void* __restrict__ gatb,
                       int layer, int k, float* __restrict__ outf,
                       const int* __restrict__ flags) {
  int isf32 = flags[0];
  int n = blockIdx.x * 4 + (threadIdx.x >> 6);
  int lane = threadIdx.x & 63;
  const int* rp = rowp + (size_t)k * (NN + 1);
  int s0 = rp[n], s1 = rp[n + 1];
  int deg = s1 - s0;
  float ad = av_d[n];
  const u32* cl = colx + (size_t)k * NE;

  // pass 1: segment max (lane-parallel, butterfly)
  float m = -INFINITY;
  for (int base = 0; base < deg; base += 64) {
    int j = base + lane;
    float e = -INFINITY;
    if (j < deg) {
      int s = (int)cl[s0 + j];
      e = av_s[s] + ad;
      e = e > 0.f ? e : 0.2f * e;
    }
    m = fmaxf(m, e);
  }
  #pragma unroll
  for (int off = 32; off; off >>= 1) m = fmaxf(m, __shfl_xor(m, off, 64));

  // pass 2: denom (lane-parallel partial sums, one butterfly)
  float den = 0.f;
  for (int base = 0; base < deg; base += 64) {
    int j = base + lane;
    if (j < deg) {
      int s = (int)cl[s0 + j];
      float e = av_s[s] + ad;
      e = e > 0.f ? e : 0.2f * e;
      den += __expf(e - m);
    }
  }
  #pragma unroll
  for (int off = 32; off; off >>= 1) den += __shfl_xor(den, off, 64);
  float di = 1.f / (den + 1e-16f);

  // pass 3: weighted accumulate; each lane owns 2 columns (bf16 h row)
  float a0 = 0.f, a1 = 0.f;
  for (int q = s0; q < s1; q++) {
    int s = (int)cl[q];                      // broadcast
    float e = av_s[s] + ad;                  // broadcast load
    e = e > 0.f ? e : 0.2f * e;
    float p = __expf(e - m);
    u32 hv = hb[(size_t)s * 64 + lane];      // coalesced 256B row
    a0 += p * bflo(hv);
    a1 += p * bfhi(hv);
  }
  float o0 = a0 * di + ldf(gatb, (size_t)layer * D + 2 * lane, isf32);
  float o1 = a1 * di + ldf(gatb, (size_t)layer * D + 2 * lane + 1, isf32);
  *(float2*)(outf + (size_t)n * D + 2 * lane) = make_float2(o0, o1);
}

// ---------------- BN pass A: column sums ----------------
__global__ void k_colsum(const float* __restrict__ tmp, float* __restrict__ colsum) {
  __shared__ float s1[256];
  int t = threadIdx.x;
  int c = t & 127;
  int half = t >> 7;
  size_t base = (size_t)blockIdx.x * 256;
  float s = 0.f;
  for (int i = half; i < 256; i += 2) {
    size_t r = base + i;
    if (r < NN) s += tmp[r * D + c];
  }
  s1[t] = s; __syncthreads();
  if (t < 128) atomicAdd(&colsum[c], s1[t] + s1[t + 128]);
}

// ---------------- BN pass B: centered second moment (mu inline) ----------------
__global__ void k_colvar(const float* __restrict__ tmp, const float* __restrict__ colsum,
                         float* __restrict__ colvar) {
  __shared__ float s1[256];
  __shared__ float ml[D];
  int t = threadIdx.x;
  if (t < D) ml[t] = colsum[t] * (1.f / NN);
  __syncthreads();
  int c = t & 127;
  int half = t >> 7;
  float mc = ml[c];
  size_t base = (size_t)blockIdx.x * 256;
  float s = 0.f;
  for (int i = half; i < 256; i += 2) {
    size_t r = base + i;
    if (r < NN) {
      float d = tmp[r * D + c] - mc;
      s += d * d;
    }
  }
  s1[t] = s; __syncthreads();
  if (t < 128) atomicAdd(&colvar[c], s1[t] + s1[t + 128]);
}

// ---------------- residual update (mu/rsig inline) ----------------
__global__ void k_update(float* __restrict__ e, const float* __restrict__ tmp,
                         const float* __restrict__ colsum, const float* __restrict__ colvar,
                         const void* __restrict__ gamma, const void* __restrict__ beta,
                         int layer, const int* __restrict__ flags) {
  int isf32 = flags[0];
  size_t idx = (size_t)blockIdx.x * 256 + threadIdx.x;
  int c0 = ((int)(idx & 31)) * 4;
  float4 t4 = ((const float4*)tmp)[idx];
  float4 e4 = ((float4*)e)[idx];
  float tb[4] = {t4.x, t4.y, t4.z, t4.w};
  float eb[4] = {e4.x, e4.y, e4.z, e4.w};
  #pragma unroll
  for (int i = 0; i < 4; i++) {
    int c = c0 + i;
    float mu = colsum[c] * (1.f / NN);
    float rs = rsqrtf(colvar[c] * (1.f / NN) + 1e-5f);
    float bn = ldf(gamma, (size_t)layer * D + c, isf32) * (tb[i] - mu) * rs
             + ldf(beta, (size_t)layer * D + c, isf32);
    bn = bn > 0.f ? bn : 0.01f * bn;
    eb[i] += bn;
  }
  ((float4*)e)[idx] = make_float4(eb[0], eb[1], eb[2], eb[3]);
}

// ---------------- rel update; final-layer writes f32 rel to out ----------------
__global__ void k_relup(const void* __restrict__ relW, const void* __restrict__ relb,
                        float* __restrict__ rel_cur, int layer, float* __restrict__ out_final,
                        const int* __restrict__ flags) {
  int isf32 = flags[0];
  __shared__ float rl[D];
  int c = threadIdx.x;
  rl[c] = rel_cur[c];
  __syncthreads();
  float acc = ldf(relb, (size_t)layer * D + c, isf32);
  size_t Wo = ((size_t)layer * D + c) * D;
  for (int kk = 0; kk < D; kk++) acc += ldf(relW, Wo + kk, isf32) * rl[kk];
  rel_cur[c] = acc;
  if (out_final) out_final[c] = acc;
}

extern "C" void kernel_launch(void* const* d_in, const int* in_sizes, int n_in,
                              void* d_out, int out_size, void* d_ws, size_t ws_size,
                              hipStream_t stream) {
  const void* feat    = d_in[0];
  const void* rel_emb = d_in[1];
  const void* edges   = d_in[2];
  const void* gatW    = d_in[3];
  const void* asrc    = d_in[4];
  const void* adst    = d_in[5];
  const void* gatb    = d_in[6];
  const void* gamma   = d_in[7];
  const void* beta    = d_in[8];
  const void* relW    = d_in[9];
  const void* relb    = d_in[10];
  float* out = (float*)d_out;     // FLOAT32: [4][NN][D] embs + [4][D] rels

  char* p = (char*)d_ws;
  auto take = [&](size_t bytes) -> void* {
    void* r = (void*)p;
    p += (bytes + 255) & ~(size_t)255;
    return r;
  };
  float* emb    = (float*)take(ND * 4);                    // 25.6 MB
  u32*   hb     = (u32*)  take(ND * 2);                    // 12.8 MB bf16-packed h
  float* tmp    = (float*)take(ND * 4);                    // 25.6 MB
  u32*   colx   = (u32*)  take((size_t)4 * NE * 4);        // 12.8 MB
  int*   rowp   = (int*)  take((size_t)4 * (NN + 1) * 4);
  int*   cur    = (int*)  take((size_t)4 * NN * 4);
  int*   deg    = (int*)  take((size_t)4 * NN * 4);
  float* av_s   = (float*)take(NN * 4);
  float* av_d   = (float*)take(NN * 4);
  float* Bm     = (float*)take(D * D * 4);
  float* wsv    = (float*)take(D * 4);
  float* wdv    = (float*)take(D * 4);
  float* relc   = (float*)take(D * 4);
  float* colsum = (float*)take(D * 4);
  float* colvar = (float*)take(D * 4);
  int*   flags  = (int*)  take(64);

  hipMemsetAsync(deg, 0, (size_t)4 * NN * 4, stream);

  k_detect<<<1, 256, 0, stream>>>(feat, edges, flags);
  k_count<<<dim3(NE / 256, 4), 256, 0, stream>>>(edges, deg, flags);
  k_scan<<<4, 256, 0, stream>>>(deg, rowp, cur);
  k_scatter<<<dim3(NE / 256, 4), 256, 0, stream>>>(edges, cur, colx, flags);

  for (int k = 0; k < 4; k++) {
    k_initk<<<(int)(ND / 4 / 256), 256, 0, stream>>>(feat, rel_emb, emb, relc, k, flags);
    for (int layer = 0; layer < 3; layer++) {
      bool last = (layer == 2);
      k_prep<<<1, 128, 0, stream>>>(gatW, asrc, adst, relc, layer, Bm, wsv, wdv, colsum, colvar, flags);
      k_gemm<<<(NN + RT - 1) / RT, 256, 0, stream>>>(emb, Bm, wsv, wdv, hb, av_s, av_d);
      if (!last) {
        k_aggf<<<NN / 4, 256, 0, stream>>>(rowp, colx, av_s, av_d, hb, gatb, layer, k, tmp, flags);
        k_colsum<<<(NN + 255) / 256, 256, 0, stream>>>(tmp, colsum);
        k_colvar<<<(NN + 255) / 256, 256, 0, stream>>>(tmp, colsum, colvar);
        k_update<<<(int)(ND / 4 / 256), 256, 0, stream>>>(emb, tmp, colsum, colvar, gamma, beta, layer, flags);
        k_relup<<<1, 128, 0, stream>>>(relW, relb, relc, layer, (float*)nullptr, flags);
      } else {
        k_aggf<<<NN / 4, 256, 0, stream>>>(rowp, colx, av_s, av_d, hb, gatb, layer, k,
                                           out + (size_t)k * ND, flags);
        k_relup<<<1, 128, 0, stream>>>(relW, relb, relc, layer, out + 4 * ND + (size_t)k * D, flags);
      }
    }
  }
}

// Round 13
// 2538.436 us; speedup vs baseline: 1.4574x; 1.3454x over previous
//
#include <hip/hip_runtime.h>

#define NN 50000
#define NE 800000
#define D  128
#define RT 32
#define NB 196                     // ceil(NN/256) scan blocks
#define ND ((size_t)NN * D)

typedef unsigned short u16;
typedef unsigned int   u32;
typedef long long      ll64;

__device__ __forceinline__ float bf2f(u16 v) {
  return __uint_as_float(((u32)v) << 16);
}
__device__ __forceinline__ u16 f2bf(float f) {
  u32 u = __float_as_uint(f);
  u32 r = u + 0x7fffu + ((u >> 16) & 1u);   // RNE
  return (u16)(r >> 16);
}
__device__ __forceinline__ float bflo(u32 u) { return __uint_as_float(u << 16); }
__device__ __forceinline__ float bfhi(u32 u) { return __uint_as_float(u & 0xffff0000u); }
__device__ __forceinline__ float ldf(const void* p, size_t i, int isf32) {
  return isf32 ? ((const float*)p)[i] : bf2f(((const u16*)p)[i]);
}
__device__ __forceinline__ int lde(const void* p, size_t i, int isi64) {
  return isi64 ? (int)((const ll64*)p)[i] : ((const int*)p)[i];
}

// flags: [0]=floats-are-f32, [1]=edges-are-i64
__global__ void k_detect(const void* __restrict__ feat, const void* __restrict__ edges,
                         int* __restrict__ flags) {
  __shared__ int cnt0, cnt1;
  int t = threadIdx.x;
  if (t == 0) { cnt0 = 0; cnt1 = 0; }
  __syncthreads();
  float v = ((const float*)feat)[t];
  float av = fabsf(v);
  if (av == 0.f || (av >= 1e-8f && av <= 1e4f)) atomicAdd(&cnt0, 1);
  if (t < 128) {
    if (((const int*)edges)[2 * t + 1] != 0) atomicAdd(&cnt1, 1);
  }
  __syncthreads();
  if (t == 0) {
    flags[0] = (cnt0 >= 240) ? 1 : 0;
    flags[1] = (cnt1 == 0) ? 1 : 0;
  }
}

// ---- per-relation init: emb(f32 ws) = features; rel_cur = rel_emb[k] ----
__global__ void k_initk(const void* __restrict__ feat, const void* __restrict__ rel_emb,
                        float* __restrict__ emb, float* __restrict__ rel_cur, int k,
                        const int* __restrict__ flags) {
  int isf32 = flags[0];
  size_t i = (size_t)blockIdx.x * 256 + threadIdx.x;
  if (isf32) {
    ((float4*)emb)[i] = ((const float4*)feat)[i];
  } else {
    uint2 v = ((const uint2*)feat)[i];
    ((float4*)emb)[i] = make_float4(bflo(v.x), bfhi(v.x), bflo(v.y), bfhi(v.y));
  }
  if (blockIdx.x == 0 && threadIdx.x < D)
    rel_cur[threadIdx.x] = ldf(rel_emb, (size_t)k * D + threadIdx.x, isf32);
}

// ---------------- CSR build ----------------
__global__ void k_count(const void* __restrict__ edges, int* __restrict__ deg, const int* __restrict__ flags) {
  int isi64 = flags[1];
  int k = blockIdx.y;
  int e = blockIdx.x * 256 + threadIdx.x;
  int dst = lde(edges, (size_t)k * 2 * NE + NE + e, isi64);
  atomicAdd(&deg[k * NN + dst], 1);
}

// scan phase A: per-block sums
__global__ void k_bsum(const int* __restrict__ deg, int* __restrict__ bsum) {
  int k = blockIdx.y, b = blockIdx.x, t = threadIdx.x;
  __shared__ int sh[256];
  int idx = b * 256 + t;
  sh[t] = (idx < NN) ? deg[k * NN + idx] : 0;
  __syncthreads();
  for (int off = 128; off; off >>= 1) {
    if (t < off) sh[t] += sh[t + off];
    __syncthreads();
  }
  if (t == 0) bsum[k * NB + b] = sh[0];
}

// scan phase B: one block scans the 196 block sums per relation -> exclusive offsets
__global__ void k_bscan(const int* __restrict__ bsum, int* __restrict__ boff) {
  __shared__ int sh[256];
  int t = threadIdx.x;
  for (int k = 0; k < 4; k++) {
    int v = (t < NB) ? bsum[k * NB + t] : 0;
    sh[t] = v;
    __syncthreads();
    for (int off = 1; off < 256; off <<= 1) {
      int a = (t >= off) ? sh[t - off] : 0;
      __syncthreads();
      sh[t] += a;
      __syncthreads();
    }
    if (t < NB) boff[k * NB + t] = sh[t] - v;   // exclusive
    __syncthreads();
  }
}

// scan phase C: local prefix + block offset -> rowp, cur
__global__ void k_place(const int* __restrict__ deg, const int* __restrict__ boff,
                        int* __restrict__ rowp, int* __restrict__ cur) {
  int k = blockIdx.y, b = blockIdx.x, t = threadIdx.x;
  __shared__ int sh[256];
  int idx = b * 256 + t;
  int v = (idx < NN) ? deg[k * NN + idx] : 0;
  sh[t] = v;
  __syncthreads();
  for (int off = 1; off < 256; off <<= 1) {
    int a = (t >= off) ? sh[t - off] : 0;
    __syncthreads();
    sh[t] += a;
    __syncthreads();
  }
  int incl = boff[k * NB + b] + sh[t];
  if (idx < NN) {
    rowp[(size_t)k * (NN + 1) + idx + 1] = incl;
    cur[k * NN + idx] = incl - v;
  }
  if (b == 0 && t == 0) rowp[(size_t)k * (NN + 1)] = 0;
}

__global__ void k_scatter(const void* __restrict__ edges, int* __restrict__ cur,
                          u16* __restrict__ colx, const int* __restrict__ flags) {
  int isi64 = flags[1];
  int k = blockIdx.y;
  int e = blockIdx.x * 256 + threadIdx.x;
  int src = lde(edges, (size_t)k * 2 * NE + e, isi64);
  int dst = lde(edges, (size_t)k * 2 * NE + NE + e, isi64);
  int pos = atomicAdd(&cur[k * NN + dst], 1);
  colx[(size_t)k * NE + pos] = (u16)src;
}

// ---- prep: Bm = diag(rel)@W; wsv/wdv = Bm@a; zero stats ----
__global__ void k_prep(const void* __restrict__ gatW, const void* __restrict__ asrc,
                       const void* __restrict__ adst, const float* __restrict__ rel_cur,
                       int layer, float* __restrict__ Bm,
                       float* __restrict__ wsv, float* __restrict__ wdv,
                       float* __restrict__ colsum, float* __restrict__ colsq,
                       const int* __restrict__ flags) {
  int isf32 = flags[0];
  int r = threadIdx.x;
  float rv = rel_cur[r];
  size_t Wo = (size_t)layer * D * D + (size_t)r * D;
  float s = 0.f, d = 0.f;
  for (int c = 0; c < D; c++) {
    float b = rv * ldf(gatW, Wo + c, isf32);
    Bm[r * D + c] = b;
    s += b * ldf(asrc, layer * D + c, isf32);
    d += b * ldf(adst, layer * D + c, isf32);
  }
  wsv[r] = s; wdv[r] = d;
  colsum[r] = 0.f; colsq[r] = 0.f;
}

// ------- GEMM: hb(bf16 packed) = x @ Bm; fused alpha epilogue -------
__launch_bounds__(256)
__global__ void k_gemm(const float* __restrict__ x, const float* __restrict__ Bm,
                       const float* __restrict__ wsv, const float* __restrict__ wdv,
                       u32* __restrict__ hb, float* __restrict__ av_s, float* __restrict__ av_d) {
  __shared__ float xl[RT * D];     // 16 KB
  __shared__ float wsl[D], wdl[D];
  int t = threadIdx.x;
  int row0 = blockIdx.x * RT;

  if (t < D) { wsl[t] = wsv[t]; wdl[t] = wdv[t]; }
  for (int i = t; i < RT * D / 4; i += 256) {
    int r = i >> 5;
    int row = row0 + r;
    float4 v = make_float4(0.f, 0.f, 0.f, 0.f);
    if (row < NN) v = ((const float4*)(x + (size_t)row * D))[i & 31];
    ((float4*)xl)[i] = v;
  }
  __syncthreads();

  int cg = t & 31, rg = t >> 5;
  float acc0[4], acc1[4], acc2[4], acc3[4];
  #pragma unroll
  for (int j = 0; j < 4; j++) { acc0[j] = 0; acc1[j] = 0; acc2[j] = 0; acc3[j] = 0; }
  const float* Bp = Bm + cg * 4;
  const float* xp = xl + (rg * 4) * D;
  for (int kk = 0; kk < D; kk += 4) {
    float4 b0 = *(const float4*)(Bp + (kk    ) * D);
    float4 b1 = *(const float4*)(Bp + (kk + 1) * D);
    float4 b2 = *(const float4*)(Bp + (kk + 2) * D);
    float4 b3 = *(const float4*)(Bp + (kk + 3) * D);
    #pragma unroll
    for (int j = 0; j < 4; j++) {
      float4 x4 = *(const float4*)(xp + j * D + kk);
      acc0[j] += x4.x * b0.x + x4.y * b1.x + x4.z * b2.x + x4.w * b3.x;
      acc1[j] += x4.x * b0.y + x4.y * b1.y + x4.z * b2.y + x4.w * b3.y;
      acc2[j] += x4.x * b0.z + x4.y * b1.z + x4.z * b2.z + x4.w * b3.z;
      acc3[j] += x4.x * b0.w + x4.y * b1.w + x4.z * b2.w + x4.w * b3.w;
    }
  }
  #pragma unroll
  for (int j = 0; j < 4; j++) {
    int row = row0 + rg * 4 + j;
    if (row < NN) {
      uint2 pk;
      pk.x = (u32)f2bf(acc0[j]) | ((u32)f2bf(acc1[j]) << 16);
      pk.y = (u32)f2bf(acc2[j]) | ((u32)f2bf(acc3[j]) << 16);
      *(uint2*)(hb + (size_t)row * 64 + cg * 2) = pk;
    }
  }
  // alpha epilogue: threads 0..31, one row each; rotated LDS reads (conflict-free)
  if (t < RT) {
    int row = row0 + t;
    if (row < NN) {
      const float* xr = xl + t * D;
      float s = 0.f, d = 0.f;
      for (int kk = 0; kk < D; kk++) {
        int c = (kk + t) & (D - 1);
        float xv = xr[c];
        s += xv * wsl[c];
        d += xv * wdl[c];
      }
      av_s[row] = s; av_d[row] = d;
    }
  }
}

// ------- fused aggregation: wave/node; single gather + shfl broadcast -------
__launch_bounds__(256)
__global__ void k_aggf(const int* __restrict__ rowp, const u16* __restrict__ colx,
                       const float* __restrict__ av_s, const float* __restrict__ av_d,
                       const u32* __restrict__ hb, const void* __restrict__ gatb,
                       int layer, int k, float* __restrict__ outf,
                       const int* __restrict__ flags) {
  int isf32 = flags[0];
  int n = blockIdx.x * 4 + (threadIdx.x >> 6);
  int lane = threadIdx.x & 63;
  const int* rp = rowp + (size_t)k * (NN + 1);
  int s0 = rp[n], s1 = rp[n + 1];
  int deg = s1 - s0;
  float ad = av_d[n];
  const u16* cl = colx + (size_t)k * NE;

  // chunk 0: per-lane src/e kept in registers (covers deg<=64, i.e. ~all nodes)
  int src0 = 0; float e0 = -INFINITY;
  if (lane < deg) {
    src0 = (int)cl[s0 + lane];
    float e = av_s[src0] + ad;
    e0 = e > 0.f ? e : 0.2f * e;
  }
  float m = e0;
  for (int base = 64; base < deg; base += 64) {   // rare overflow chunks
    int j = base + lane;
    if (j < deg) {
      int s = (int)cl[s0 + j];
      float e = av_s[s] + ad;
      e = e > 0.f ? e : 0.2f * e;
      m = fmaxf(m, e);
    }
  }
  #pragma unroll
  for (int off = 32; off; off >>= 1) m = fmaxf(m, __shfl_xor(m, off, 64));

  float den = 0.f, a0 = 0.f, a1 = 0.f;
  {
    float p = (lane < deg) ? __expf(e0 - m) : 0.f;
    den += p;
    int cnt = min(64, deg);
    for (int jj = 0; jj < cnt; jj++) {
      float ps = __shfl(p, jj, 64);
      int   ss = __shfl(src0, jj, 64);
      u32 hv = hb[(size_t)ss * 64 + lane];   // coalesced 256B row
      a0 += ps * bflo(hv);
      a1 += ps * bfhi(hv);
    }
  }
  for (int base = 64; base < deg; base += 64) {
    int j = base + lane;
    int src = 0; float p = 0.f;
    if (j < deg) {
      src = (int)cl[s0 + j];
      float e = av_s[src] + ad;
      e = e > 0.f ? e : 0.2f * e;
      p = __expf(e - m);
    }
    den += p;
    int cnt = min(64, deg - base);
    for (int jj = 0; jj < cnt; jj++) {
      float ps = __shfl(p, jj, 64);
      int   ss = __shfl(src, jj, 64);
      u32 hv = hb[(size_t)ss * 64 + lane];
      a0 += ps * bflo(hv);
      a1 += ps * bfhi(hv);
    }
  }
  #pragma unroll
  for (int off = 32; off; off >>= 1) den += __shfl_xor(den, off, 64);
  float di = 1.f / (den + 1e-16f);
  float o0 = a0 * di + ldf(gatb, (size_t)layer * D + 2 * lane, isf32);
  float o1 = a1 * di + ldf(gatb, (size_t)layer * D + 2 * lane + 1, isf32);
  *(float2*)(outf + (size_t)n * D + 2 * lane) = make_float2(o0, o1);
}

// ---------------- BN stats: single pass (sum + sumsq) ----------------
__global__ void k_stats(const float* __restrict__ tmp, float* __restrict__ colsum,
                        float* __restrict__ colsq) {
  __shared__ float s1[256], s2[256];
  int t = threadIdx.x;
  int c = t & 127;
  int half = t >> 7;
  size_t base = (size_t)blockIdx.x * 256;
  float s = 0.f, q = 0.f;
  for (int i = half; i < 256; i += 2) {
    size_t r = base + i;
    if (r < NN) {
      float v = tmp[r * D + c];
      s += v; q += v * v;
    }
  }
  s1[t] = s; s2[t] = q; __syncthreads();
  if (t < 128) {
    atomicAdd(&colsum[c], s1[t] + s1[t + 128]);
    atomicAdd(&colsq[c],  s2[t] + s2[t + 128]);
  }
}

// ---------------- residual update (mu/rsig inline from sum/sumsq) ----------------
__global__ void k_update(float* __restrict__ e, const float* __restrict__ tmp,
                         const float* __restrict__ colsum, const float* __restrict__ colsq,
                         const void* __restrict__ gamma, const void* __restrict__ beta,
                         int layer, const int* __restrict__ flags) {
  int isf32 = flags[0];
  size_t idx = (size_t)blockIdx.x * 256 + threadIdx.x;
  int c0 = ((int)(idx & 31)) * 4;
  float4 t4 = ((const float4*)tmp)[idx];
  float4 e4 = ((float4*)e)[idx];
  float tb[4] = {t4.x, t4.y, t4.z, t4.w};
  float eb[4] = {e4.x, e4.y, e4.z, e4.w};
  #pragma unroll
  for (int i = 0; i < 4; i++) {
    int c = c0 + i;
    float mu = colsum[c] * (1.f / NN);
    float var = colsq[c] * (1.f / NN) - mu * mu;
    float rs = rsqrtf(fmaxf(var, 0.f) + 1e-5f);
    float bn = ldf(gamma, (size_t)layer * D + c, isf32) * (tb[i] - mu) * rs
             + ldf(beta, (size_t)layer * D + c, isf32);
    bn = bn > 0.f ? bn : 0.01f * bn;
    eb[i] += bn;
  }
  ((float4*)e)[idx] = make_float4(eb[0], eb[1], eb[2], eb[3]);
}

// ---------------- rel update; final-layer writes f32 rel to out ----------------
__global__ void k_relup(const void* __restrict__ relW, const void* __restrict__ relb,
                        float* __restrict__ rel_cur, int layer, float* __restrict__ out_final,
                        const int* __restrict__ flags) {
  int isf32 = flags[0];
  __shared__ float rl[D];
  int c = threadIdx.x;
  rl[c] = rel_cur[c];
  __syncthreads();
  float acc = ldf(relb, (size_t)layer * D + c, isf32);
  size_t Wo = ((size_t)layer * D + c) * D;
  for (int kk = 0; kk < D; kk++) acc += ldf(relW, Wo + kk, isf32) * rl[kk];
  rel_cur[c] = acc;
  if (out_final) out_final[c] = acc;
}

extern "C" void kernel_launch(void* const* d_in, const int* in_sizes, int n_in,
                              void* d_out, int out_size, void* d_ws, size_t ws_size,
                              hipStream_t stream) {
  const void* feat    = d_in[0];
  const void* rel_emb = d_in[1];
  const void* edges   = d_in[2];
  const void* gatW    = d_in[3];
  const void* asrc    = d_in[4];
  const void* adst    = d_in[5];
  const void* gatb    = d_in[6];
  const void* gamma   = d_in[7];
  const void* beta    = d_in[8];
  const void* relW    = d_in[9];
  const void* relb    = d_in[10];
  float* out = (float*)d_out;     // FLOAT32: [4][NN][D] embs + [4][D] rels

  char* p = (char*)d_ws;
  auto take = [&](size_t bytes) -> void* {
    void* r = (void*)p;
    p += (bytes + 255) & ~(size_t)255;
    return r;
  };
  float* emb    = (float*)take(ND * 4);                    // 25.6 MB
  u32*   hb     = (u32*)  take(ND * 2);                    // 12.8 MB bf16-packed h
  float* tmp    = (float*)take(ND * 4);                    // 25.6 MB
  u16*   colx   = (u16*)  take((size_t)4 * NE * 2);        // 6.4 MB
  int*   rowp   = (int*)  take((size_t)4 * (NN + 1) * 4);
  int*   cur    = (int*)  take((size_t)4 * NN * 4);
  int*   deg    = (int*)  take((size_t)4 * NN * 4);
  int*   bsum   = (int*)  take((size_t)4 * NB * 4);
  int*   boff   = (int*)  take((size_t)4 * NB * 4);
  float* av_s   = (float*)take(NN * 4);
  float* av_d   = (float*)take(NN * 4);
  float* Bm     = (float*)take(D * D * 4);
  float* wsv    = (float*)take(D * 4);
  float* wdv    = (float*)take(D * 4);
  float* relc   = (float*)take(D * 4);
  float* colsum = (float*)take(D * 4);
  float* colsq  = (float*)take(D * 4);
  int*   flags  = (int*)  take(64);

  hipMemsetAsync(deg, 0, (size_t)4 * NN * 4, stream);

  k_detect<<<1, 256, 0, stream>>>(feat, edges, flags);
  k_count<<<dim3(NE / 256, 4), 256, 0, stream>>>(edges, deg, flags);
  k_bsum<<<dim3(NB, 4), 256, 0, stream>>>(deg, bsum);
  k_bscan<<<1, 256, 0, stream>>>(bsum, boff);
  k_place<<<dim3(NB, 4), 256, 0, stream>>>(deg, boff, rowp, cur);
  k_scatter<<<dim3(NE / 256, 4), 256, 0, stream>>>(edges, cur, colx, flags);

  for (int k = 0; k < 4; k++) {
    k_initk<<<(int)(ND / 4 / 256), 256, 0, stream>>>(feat, rel_emb, emb, relc, k, flags);
    for (int layer = 0; layer < 3; layer++) {
      bool last = (layer == 2);
      k_prep<<<1, 128, 0, stream>>>(gatW, asrc, adst, relc, layer, Bm, wsv, wdv, colsum, colsq, flags);
      k_gemm<<<(NN + RT - 1) / RT, 256, 0, stream>>>(emb, Bm, wsv, wdv, hb, av_s, av_d);
      if (!last) {
        k_aggf<<<NN / 4, 256, 0, stream>>>(rowp, colx, av_s, av_d, hb, gatb, layer, k, tmp, flags);
        k_stats<<<(NN + 255) / 256, 256, 0, stream>>>(tmp, colsum, colsq);
        k_update<<<(int)(ND / 4 / 256), 256, 0, stream>>>(emb, tmp, colsum, colsq, gamma, beta, layer, flags);
        k_relup<<<1, 128, 0, stream>>>(relW, relb, relc, layer, (float*)nullptr, flags);
      } else {
        k_aggf<<<NN / 4, 256, 0, stream>>>(rowp, colx, av_s, av_d, hb, gatb, layer, k,
                                           out + (size_t)k * ND, flags);
        k_relup<<<1, 128, 0, stream>>>(relW, relb, relc, layer, out + 4 * ND + (size_t)k * D, flags);
      }
    }
  }
}